// Round 5
// baseline (255.438 us; speedup 1.0000x reference)
//
#include <hip/hip_runtime.h>
#include <hip/hip_bf16.h>
#include <math.h>

#define NN 1024
#define BB 64
#define LL 197
#define LP 224
#define DD 768
#define PSTRIDE 228  // plds row stride in elements (224 + 4 pad)

typedef __attribute__((ext_vector_type(8))) short short8;
typedef __attribute__((ext_vector_type(4))) float f32x4;

constexpr float LN_EPS = 1e-5f;
constexpr float NORM_EPS = 1e-12f;
constexpr float EPS = 1e-8f;

__device__ __forceinline__ float waveSum(float v) {
#pragma unroll
    for (int m = 32; m >= 1; m >>= 1) v += __shfl_xor(v, m, 64);
    return v;
}
__device__ __forceinline__ float grpSum(float v) {
#pragma unroll
    for (int m = 8; m >= 1; m >>= 1) v += __shfl_xor(v, m, 64);
    return v;
}
__device__ __forceinline__ float grpMax(float v) {
#pragma unroll
    for (int m = 8; m >= 1; m >>= 1) v = fmaxf(v, __shfl_xor(v, m, 64));
    return v;
}

__device__ __forceinline__ unsigned short f2bf(float f) {
    __hip_bfloat16 h = __float2bfloat16(f);
    return reinterpret_cast<unsigned short&>(h);
}
__device__ __forceinline__ float bf2f(unsigned short u) {
    unsigned int x = ((unsigned int)u) << 16;
    return reinterpret_cast<float&>(x);
}

__device__ __forceinline__ void gl_lds16(const void* g, void* l) {
    __builtin_amdgcn_global_load_lds(
        (const __attribute__((address_space(1))) unsigned int*)g,
        (__attribute__((address_space(3))) unsigned int*)l, 16, 0, 0);
}

// Text LayerNorm -> bf16 + qinv = 1/max(||y||,eps)
__global__ __launch_bounds__(256) void ln_kernel(
    const float* __restrict__ x, __hip_bfloat16* __restrict__ y,
    const float* __restrict__ gamma, const float* __restrict__ beta,
    float* __restrict__ qinv) {
    const int row = blockIdx.x;
    const int tid = threadIdx.x;
    const float* xr = x + (size_t)row * DD;
    __hip_bfloat16* yr = y + (size_t)row * DD;

    float v[3];
    float s = 0.f, ss = 0.f;
#pragma unroll
    for (int c = 0; c < 3; c++) {
        float t = xr[tid + 256 * c];
        v[c] = t; s += t; ss += t * t;
    }
    __shared__ float red[8];
    s = waveSum(s); ss = waveSum(ss);
    const int w = tid >> 6;
    if ((tid & 63) == 0) { red[w] = s; red[4 + w] = ss; }
    __syncthreads();
    s = red[0] + red[1] + red[2] + red[3];
    ss = red[4] + red[5] + red[6] + red[7];
    const float mean = s * (1.f / DD);
    const float var = ss * (1.f / DD) - mean * mean;
    const float rs = rsqrtf(var + LN_EPS);

    float q = 0.f;
#pragma unroll
    for (int c = 0; c < 3; c++) {
        const int d = tid + 256 * c;
        float t = (v[c] - mean) * rs * gamma[d] + beta[d];
        __hip_bfloat16 hb = __float2bfloat16(t);
        yr[d] = hb;
        float tb = __bfloat162float(hb);
        q += tb * tb;
    }
    __syncthreads();
    q = waveSum(q);
    if ((tid & 63) == 0) red[w] = q;
    __syncthreads();
    if (tid == 0) {
        float n2 = red[0] + red[1] + red[2] + red[3];
        qinv[row] = 1.f / fmaxf(sqrtf(n2), NORM_EPS);
    }
}

// Vision LayerNorm into padded [B, LP, D] layout; pad rows (l>=LL) zero-filled.
__global__ __launch_bounds__(256) void ln_vis_kernel(
    const float* __restrict__ x, __hip_bfloat16* __restrict__ y,
    const float* __restrict__ gamma, const float* __restrict__ beta) {
    const int id = blockIdx.x;
    const int b = id / LP, l = id - b * LP;
    const int tid = threadIdx.x;
    __hip_bfloat16* yr = y + ((size_t)b * LP + l) * DD;
    if (l >= LL) {
#pragma unroll
        for (int c = 0; c < 3; c++) yr[tid + 256 * c] = __float2bfloat16(0.f);
        return;
    }
    const float* xr = x + ((size_t)b * LL + l) * DD;

    float v[3];
    float s = 0.f, ss = 0.f;
#pragma unroll
    for (int c = 0; c < 3; c++) {
        float t = xr[tid + 256 * c];
        v[c] = t; s += t; ss += t * t;
    }
    __shared__ float red[8];
    s = waveSum(s); ss = waveSum(ss);
    const int w = tid >> 6;
    if ((tid & 63) == 0) { red[w] = s; red[4 + w] = ss; }
    __syncthreads();
    s = red[0] + red[1] + red[2] + red[3];
    ss = red[4] + red[5] + red[6] + red[7];
    const float mean = s * (1.f / DD);
    const float var = ss * (1.f / DD) - mean * mean;
    const float rs = rsqrtf(var + LN_EPS);
#pragma unroll
    for (int c = 0; c < 3; c++) {
        const int d = tid + 256 * c;
        yr[d] = __float2bfloat16((v[c] - mean) * rs * gamma[d] + beta[d]);
    }
}

// G[b] = vt_b . vt_b^T  [LP x LP] bf16. Grid (14, 64).
__global__ __launch_bounds__(256) void gram_kernel(
    const __hip_bfloat16* __restrict__ vt, __hip_bfloat16* __restrict__ G) {
    const int rb = blockIdx.x, b = blockIdx.y;
    const int tid = threadIdx.x, w = tid >> 6, lane = tid & 63;
    const short* vtb = (const short*)(vt + (size_t)b * LP * DD);
    const int kof = (lane >> 4) * 8;

    short8 a[24];
    const int arow = rb * 16 + (lane & 15);
#pragma unroll
    for (int ks = 0; ks < 24; ks++)
        a[ks] = *(const short8*)(vtb + (size_t)arow * DD + ks * 32 + kof);

    for (int cb = w; cb < 14; cb += 4) {
        f32x4 c = {0.f, 0.f, 0.f, 0.f};
        const int brow = cb * 16 + (lane & 15);
#pragma unroll
        for (int ks = 0; ks < 24; ks++) {
            short8 bf = *(const short8*)(vtb + (size_t)brow * DD + ks * 32 + kof);
            c = __builtin_amdgcn_mfma_f32_16x16x32_bf16(a[ks], bf, c, 0, 0, 0);
        }
        __hip_bfloat16* Gb = G + ((size_t)b * LP + rb * 16) * LP + cb * 16;
        const int col = lane & 15, rg = (lane >> 4) * 4;
#pragma unroll
        for (int r = 0; r < 4; r++) Gb[(size_t)(rg + r) * LP + col] = __float2bfloat16(c[r]);
    }
}

// Fused main: S = tf.vt^T (K-sliced), softmax, num, T = P.G, den, logits.
// Grid (16, 64), 256 thr. Wave w owns l-blocks {w, w+4, w+8, w+12} for ALL 4 n-blocks.
// LDS: plds [64][228] bf16 (29184 B) overlaid by 2x14KB vt slice dbuf; +3KB exchange.
__global__ __launch_bounds__(256, 4) void main_kernel(
    const __hip_bfloat16* __restrict__ tf, const __hip_bfloat16* __restrict__ vt,
    const __hip_bfloat16* __restrict__ G, const float* __restrict__ qinv,
    float* __restrict__ logits) {
    const int b = blockIdx.y;
    const int n0 = blockIdx.x * 64;
    const int tid = threadIdx.x, w = tid >> 6, lane = tid & 63;
    const int g = lane >> 4, c = lane & 15;

    __shared__ __align__(16) unsigned char smem[29184 + 3072];
    unsigned short* plds = (unsigned short*)smem;            // [64][PSTRIDE]
    float* mx = (float*)(smem + 29184);                      // [64][4]
    float* sm = mx + 256;                                    // [64][4]
    float* nm = sm + 256;                                    // [64][4]

    const short* tfp = (const short*)tf;
    const char* vtbc = (const char*)(vt + (size_t)b * LP * DD);

    // ---- Stage 1: S = tf . vt^T, K-sliced (24 slices of K=32) ----
    // LDS slice buffer: [224 rows][64 B], granule-swizzled: phys granule = j ^ ((r ^ r>>2) & 3)
#define STAGE(ks, bp)                                                           \
    {                                                                           \
        _Pragma("unroll")                                                       \
        for (int i_ = 0; i_ < 4; i_++) {                                        \
            const int cno_ = w + 4 * i_;                                        \
            if (cno_ < 14) {                                                    \
                const int r_ = cno_ * 16 + (lane >> 2);                         \
                const int j_ = lane & 3;                                        \
                const int sj_ = j_ ^ ((r_ ^ (r_ >> 2)) & 3);                    \
                gl_lds16(vtbc + (size_t)r_ * 1536 + (size_t)(ks) * 64 + sj_ * 16, \
                         (bp) + cno_ * 1024 + lane * 16);                       \
            }                                                                   \
        }                                                                       \
    }

    f32x4 acc[4][4];  // [i = lb slot][nb]
#pragma unroll
    for (int i = 0; i < 4; i++)
#pragma unroll
        for (int nb = 0; nb < 4; nb++) acc[i][nb] = {0.f, 0.f, 0.f, 0.f};

    STAGE(0, smem);
    asm volatile("s_waitcnt vmcnt(0)" ::: "memory");
    __syncthreads();

    for (int ks = 0; ks < 24; ks++) {
        const unsigned char* bp = smem + (ks & 1) * 14336;
        if (ks < 23) STAGE(ks + 1, smem + ((ks + 1) & 1) * 14336);

        short8 a[4];
#pragma unroll
        for (int nb = 0; nb < 4; nb++)
            a[nb] = *(const short8*)(tfp + (size_t)(n0 + nb * 16 + c) * DD + ks * 32 + g * 8);

#pragma unroll
        for (int i = 0; i < 4; i++) {
            const int lb = w + 4 * i;
            if (lb < 14) {
                const int r = lb * 16 + c;
                const int phys = r * 64 + ((g ^ ((r ^ (r >> 2)) & 3)) * 16);
                short8 bf = *(const short8*)(bp + phys);
#pragma unroll
                for (int nb = 0; nb < 4; nb++)
                    acc[i][nb] = __builtin_amdgcn_mfma_f32_16x16x32_bf16(a[nb], bf, acc[i][nb], 0, 0, 0);
            }
        }
        asm volatile("s_waitcnt vmcnt(0)" ::: "memory");
        __syncthreads();
    }
#undef STAGE

    // ---- Stage 2: softmax over l (cross-wave: waves hold disjoint l-columns) ----
    const float inv_sqrtD = 0.0360843918f;
    float mp[4][4];
#pragma unroll
    for (int nb = 0; nb < 4; nb++)
#pragma unroll
        for (int r = 0; r < 4; r++) mp[nb][r] = -1e30f;
#pragma unroll
    for (int i = 0; i < 4; i++) {
        const int lb = w + 4 * i;
        if (lb < 14) {
            const int l = lb * 16 + c;
            if (l < LL) {
#pragma unroll
                for (int nb = 0; nb < 4; nb++)
#pragma unroll
                    for (int r = 0; r < 4; r++) mp[nb][r] = fmaxf(mp[nb][r], acc[i][nb][r]);
            }
        }
    }
#pragma unroll
    for (int nb = 0; nb < 4; nb++)
#pragma unroll
        for (int r = 0; r < 4; r++) mp[nb][r] = grpMax(mp[nb][r]);
    if (c == 0) {
#pragma unroll
        for (int nb = 0; nb < 4; nb++)
#pragma unroll
            for (int r = 0; r < 4; r++) mx[(nb * 16 + g * 4 + r) * 4 + w] = mp[nb][r];
    }
    __syncthreads();
    float mf[4][4];
#pragma unroll
    for (int nb = 0; nb < 4; nb++)
#pragma unroll
        for (int r = 0; r < 4; r++) {
            const int row = nb * 16 + g * 4 + r;
            mf[nb][r] = fmaxf(fmaxf(mx[row * 4 + 0], mx[row * 4 + 1]),
                              fmaxf(mx[row * 4 + 2], mx[row * 4 + 3]));
        }

    float sp[4][4], np[4][4];
#pragma unroll
    for (int nb = 0; nb < 4; nb++)
#pragma unroll
        for (int r = 0; r < 4; r++) { sp[nb][r] = 0.f; np[nb][r] = 0.f; }
#pragma unroll
    for (int i = 0; i < 4; i++) {
        const int lb = w + 4 * i;
        if (lb < 14) {
            const int l = lb * 16 + c;
#pragma unroll
            for (int nb = 0; nb < 4; nb++)
#pragma unroll
                for (int r = 0; r < 4; r++) {
                    const float raw = acc[i][nb][r];
                    const float p = (l < LL) ? __expf((raw - mf[nb][r]) * inv_sqrtD) : 0.f;
                    acc[i][nb][r] = p;
                    sp[nb][r] += p;
                    np[nb][r] += p * raw;
                }
        }
    }
#pragma unroll
    for (int nb = 0; nb < 4; nb++)
#pragma unroll
        for (int r = 0; r < 4; r++) { sp[nb][r] = grpSum(sp[nb][r]); np[nb][r] = grpSum(np[nb][r]); }
    if (c == 0) {
#pragma unroll
        for (int nb = 0; nb < 4; nb++)
#pragma unroll
            for (int r = 0; r < 4; r++) {
                const int row = nb * 16 + g * 4 + r;
                sm[row * 4 + w] = sp[nb][r];
                nm[row * 4 + w] = np[nb][r];
            }
    }
    __syncthreads();  // also: all stage-1 dbuf reads done -> safe to overlay plds

    float invs[4][4];
#pragma unroll
    for (int nb = 0; nb < 4; nb++)
#pragma unroll
        for (int r = 0; r < 4; r++) {
            const int row = nb * 16 + g * 4 + r;
            const float ssum = sm[row * 4 + 0] + sm[row * 4 + 1] + sm[row * 4 + 2] + sm[row * 4 + 3];
            invs[nb][r] = 1.f / ssum;
        }

    // write normalized P (bf16) to plds [64][PSTRIDE]
#pragma unroll
    for (int i = 0; i < 4; i++) {
        const int lb = w + 4 * i;
        if (lb < 14) {
#pragma unroll
            for (int nb = 0; nb < 4; nb++)
#pragma unroll
                for (int r = 0; r < 4; r++)
                    plds[(size_t)(nb * 16 + g * 4 + r) * PSTRIDE + lb * 16 + c] =
                        f2bf(acc[i][nb][r] * invs[nb][r]);
        }
    }
    __syncthreads();

    // ---- Stage 3: T = P.G (lb-outer, G rows hoisted), den = sum P*T ----
    const short* Gb = (const short*)(G + (size_t)b * LP * LP);
    float den[4][4];
#pragma unroll
    for (int nb = 0; nb < 4; nb++)
#pragma unroll
        for (int r = 0; r < 4; r++) den[nb][r] = 0.f;

#pragma unroll
    for (int i = 0; i < 4; i++) {
        const int lb = w + 4 * i;
        if (lb < 14) {
            short8 gbv[7];
#pragma unroll
            for (int kb = 0; kb < 7; kb++)
                gbv[kb] = *(const short8*)(Gb + (size_t)(lb * 16 + c) * LP + kb * 32 + g * 8);
#pragma unroll
            for (int nb = 0; nb < 4; nb++) {
                f32x4 t = {0.f, 0.f, 0.f, 0.f};
#pragma unroll
                for (int kb = 0; kb < 7; kb++) {
                    short8 pa = *(const short8*)(plds + (size_t)(nb * 16 + c) * PSTRIDE + kb * 32 + g * 8);
                    t = __builtin_amdgcn_mfma_f32_16x16x32_bf16(pa, gbv[kb], t, 0, 0, 0);
                }
#pragma unroll
                for (int r = 0; r < 4; r++) {
                    const float P = bf2f(plds[(size_t)(nb * 16 + g * 4 + r) * PSTRIDE + lb * 16 + c]);
                    den[nb][r] += P * t[r];
                }
            }
        }
    }

    // cross-wave den reduce + epilogue
#pragma unroll
    for (int nb = 0; nb < 4; nb++)
#pragma unroll
        for (int r = 0; r < 4; r++) den[nb][r] = grpSum(den[nb][r]);
    __syncthreads();
    if (c == 0) {
#pragma unroll
        for (int nb = 0; nb < 4; nb++)
#pragma unroll
            for (int r = 0; r < 4; r++) mx[(nb * 16 + g * 4 + r) * 4 + w] = den[nb][r];
    }
    __syncthreads();
    if (tid < 64) {
        const int row = tid;
        const int n = n0 + row;
        const float dsum = mx[row * 4 + 0] + mx[row * 4 + 1] + mx[row * 4 + 2] + mx[row * 4 + 3];
        const float ssum = sm[row * 4 + 0] + sm[row * 4 + 1] + sm[row * 4 + 2] + sm[row * 4 + 3];
        const float nsum = nm[row * 4 + 0] + nm[row * 4 + 1] + nm[row * 4 + 2] + nm[row * 4 + 3];
        const float num = nsum / ssum;
        const float dn = fmaxf(sqrtf(fmaxf(dsum, 0.f)), NORM_EPS);
        logits[(size_t)n * BB + b] = num * qinv[n] / dn;
    }
}

__global__ __launch_bounds__(64) void loss_row_kernel(
    const float* __restrict__ logits, const int* __restrict__ gm,
    const float* __restrict__ logtemp, float* __restrict__ scaled,
    float* __restrict__ posv, float* __restrict__ rowloss) {
    const int n = blockIdx.x;
    const int b = threadIdx.x;
    const float invtemp = 1.f / expf(logtemp[0]);
    const float e = expf(logits[(size_t)n * BB + b] * invtemp);
    scaled[(size_t)n * BB + b] = e;
    const float sum = waveSum(e);
    const int g = gm[n];
    const float pos = __shfl(e, g, 64);
    if (b == 0) {
        posv[n] = pos;
        rowloss[n] = -logf(pos / (sum + EPS) + EPS);
    }
}

__global__ __launch_bounds__(256) void colsum_kernel(
    const float* __restrict__ scaled, const int* __restrict__ gm,
    float* __restrict__ colsum, float* __restrict__ poscol) {
    const int b = blockIdx.x;
    const int tid = threadIdx.x;
    float s = 0.f, p = 0.f;
    for (int n = tid; n < NN; n += 256) {
        const float e = scaled[(size_t)n * BB + b];
        s += e;
        if (gm[n] == b) p += e;
    }
    s = waveSum(s); p = waveSum(p);
    __shared__ float red[8];
    const int w = tid >> 6;
    if ((tid & 63) == 0) { red[w] = s; red[4 + w] = p; }
    __syncthreads();
    if (tid == 0) {
        colsum[b] = red[0] + red[1] + red[2] + red[3];
        poscol[b] = red[4] + red[5] + red[6] + red[7];
    }
}

__global__ __launch_bounds__(1024) void final_kernel(
    const float* __restrict__ posv, const float* __restrict__ rowloss,
    const float* __restrict__ colsum, const float* __restrict__ poscol,
    const int* __restrict__ gm, float* __restrict__ out) {
    const int n = threadIdx.x;
    const int g = gm[n];
    const float pos = posv[n];
    const float sum_neg = colsum[g] - poscol[g];
    const float cl = -logf(pos / (pos + sum_neg + EPS) + EPS);
    float v = rowloss[n] + cl;
    v = waveSum(v);
    __shared__ float red[16];
    if ((n & 63) == 0) red[n >> 6] = v;
    __syncthreads();
    if (n == 0) {
        float s = 0.f;
#pragma unroll
        for (int i = 0; i < 16; i++) s += red[i];
        out[0] = s / (2.f * NN);
    }
}

extern "C" void kernel_launch(void* const* d_in, const int* in_sizes, int n_in,
                              void* d_out, int out_size, void* d_ws, size_t ws_size,
                              hipStream_t stream) {
    const float* text = (const float*)d_in[0];
    const float* vis = (const float*)d_in[1];
    const int* gm = (const int*)d_in[2];
    const float* gamma = (const float*)d_in[3];
    const float* beta = (const float*)d_in[4];
    const float* logtemp = (const float*)d_in[5];
    float* out = (float*)d_out;

    char* w = (char*)d_ws;
    __hip_bfloat16* tf = (__hip_bfloat16*)w;             w += (size_t)NN * DD * 2;
    __hip_bfloat16* vt = (__hip_bfloat16*)w;             w += (size_t)BB * LP * DD * 2;
    __hip_bfloat16* G  = (__hip_bfloat16*)w;             w += (size_t)BB * LP * LP * 2;
    float* qinv    = (float*)w;  w += (size_t)NN * 4;
    float* logits  = (float*)w;  w += (size_t)NN * BB * 4;
    float* scaled  = (float*)w;  w += (size_t)NN * BB * 4;
    float* posv    = (float*)w;  w += (size_t)NN * 4;
    float* rowloss = (float*)w;  w += (size_t)NN * 4;
    float* colsum  = (float*)w;  w += (size_t)BB * 4;
    float* poscol  = (float*)w;  w += (size_t)BB * 4;

    ln_kernel<<<NN, 256, 0, stream>>>(text, tf, gamma, beta, qinv);
    ln_vis_kernel<<<BB * LP, 256, 0, stream>>>(vis, vt, gamma, beta);

    gram_kernel<<<dim3(14, BB), 256, 0, stream>>>(vt, G);
    main_kernel<<<dim3(NN / 64, BB), 256, 0, stream>>>(tf, vt, G, qinv, logits);

    loss_row_kernel<<<NN, 64, 0, stream>>>(logits, gm, logtemp, scaled, posv, rowloss);
    colsum_kernel<<<BB, 256, 0, stream>>>(scaled, gm, colsum, poscol);
    final_kernel<<<1, 1024, 0, stream>>>(posv, rowloss, colsum, poscol, gm, out);
}

// Round 6
// 230.089 us; speedup vs baseline: 1.1102x; 1.1102x over previous
//
#include <hip/hip_runtime.h>
#include <hip/hip_bf16.h>
#include <math.h>

#define NN 1024
#define BB 64
#define LL 197
#define LP 224
#define DD 768
#define PSTRIDE 228  // plds row stride in elements (224 + 4 pad)

typedef __attribute__((ext_vector_type(8))) short short8;
typedef __attribute__((ext_vector_type(4))) float f32x4;

constexpr float LN_EPS = 1e-5f;
constexpr float NORM_EPS = 1e-12f;
constexpr float EPS = 1e-8f;

__device__ __forceinline__ float waveSum(float v) {
#pragma unroll
    for (int m = 32; m >= 1; m >>= 1) v += __shfl_xor(v, m, 64);
    return v;
}
__device__ __forceinline__ float grpSum(float v) {
#pragma unroll
    for (int m = 8; m >= 1; m >>= 1) v += __shfl_xor(v, m, 64);
    return v;
}
__device__ __forceinline__ float grpMax(float v) {
#pragma unroll
    for (int m = 8; m >= 1; m >>= 1) v = fmaxf(v, __shfl_xor(v, m, 64));
    return v;
}

__device__ __forceinline__ unsigned short f2bf(float f) {
    __hip_bfloat16 h = __float2bfloat16(f);
    return reinterpret_cast<unsigned short&>(h);
}

// Text LayerNorm -> bf16 + qinv = 1/max(||y||,eps)
__global__ __launch_bounds__(256) void ln_kernel(
    const float* __restrict__ x, __hip_bfloat16* __restrict__ y,
    const float* __restrict__ gamma, const float* __restrict__ beta,
    float* __restrict__ qinv) {
    const int row = blockIdx.x;
    const int tid = threadIdx.x;
    const float* xr = x + (size_t)row * DD;
    __hip_bfloat16* yr = y + (size_t)row * DD;

    float v[3];
    float s = 0.f, ss = 0.f;
#pragma unroll
    for (int c = 0; c < 3; c++) {
        float t = xr[tid + 256 * c];
        v[c] = t; s += t; ss += t * t;
    }
    __shared__ float red[8];
    s = waveSum(s); ss = waveSum(ss);
    const int w = tid >> 6;
    if ((tid & 63) == 0) { red[w] = s; red[4 + w] = ss; }
    __syncthreads();
    s = red[0] + red[1] + red[2] + red[3];
    ss = red[4] + red[5] + red[6] + red[7];
    const float mean = s * (1.f / DD);
    const float var = ss * (1.f / DD) - mean * mean;
    const float rs = rsqrtf(var + LN_EPS);

    float q = 0.f;
#pragma unroll
    for (int c = 0; c < 3; c++) {
        const int d = tid + 256 * c;
        float t = (v[c] - mean) * rs * gamma[d] + beta[d];
        __hip_bfloat16 hb = __float2bfloat16(t);
        yr[d] = hb;
        float tb = __bfloat162float(hb);
        q += tb * tb;
    }
    __syncthreads();
    q = waveSum(q);
    if ((tid & 63) == 0) red[w] = q;
    __syncthreads();
    if (tid == 0) {
        float n2 = red[0] + red[1] + red[2] + red[3];
        qinv[row] = 1.f / fmaxf(sqrtf(n2), NORM_EPS);
    }
}

// Vision LayerNorm into padded [B, LP, D] layout; pad rows (l>=LL) zero-filled.
__global__ __launch_bounds__(256) void ln_vis_kernel(
    const float* __restrict__ x, __hip_bfloat16* __restrict__ y,
    const float* __restrict__ gamma, const float* __restrict__ beta) {
    const int id = blockIdx.x;
    const int b = id / LP, l = id - b * LP;
    const int tid = threadIdx.x;
    __hip_bfloat16* yr = y + ((size_t)b * LP + l) * DD;
    if (l >= LL) {
#pragma unroll
        for (int c = 0; c < 3; c++) yr[tid + 256 * c] = __float2bfloat16(0.f);
        return;
    }
    const float* xr = x + ((size_t)b * LL + l) * DD;

    float v[3];
    float s = 0.f, ss = 0.f;
#pragma unroll
    for (int c = 0; c < 3; c++) {
        float t = xr[tid + 256 * c];
        v[c] = t; s += t; ss += t * t;
    }
    __shared__ float red[8];
    s = waveSum(s); ss = waveSum(ss);
    const int w = tid >> 6;
    if ((tid & 63) == 0) { red[w] = s; red[4 + w] = ss; }
    __syncthreads();
    s = red[0] + red[1] + red[2] + red[3];
    ss = red[4] + red[5] + red[6] + red[7];
    const float mean = s * (1.f / DD);
    const float var = ss * (1.f / DD) - mean * mean;
    const float rs = rsqrtf(var + LN_EPS);
#pragma unroll
    for (int c = 0; c < 3; c++) {
        const int d = tid + 256 * c;
        yr[d] = __float2bfloat16((v[c] - mean) * rs * gamma[d] + beta[d]);
    }
}

// G[b] = vt_b . vt_b^T  [LP x LP] bf16. Grid (14, 64).
__global__ __launch_bounds__(256) void gram_kernel(
    const __hip_bfloat16* __restrict__ vt, __hip_bfloat16* __restrict__ G) {
    const int rb = blockIdx.x, b = blockIdx.y;
    const int tid = threadIdx.x, w = tid >> 6, lane = tid & 63;
    const short* vtb = (const short*)(vt + (size_t)b * LP * DD);
    const int kof = (lane >> 4) * 8;

    short8 a[24];
    const int arow = rb * 16 + (lane & 15);
#pragma unroll
    for (int ks = 0; ks < 24; ks++)
        a[ks] = *(const short8*)(vtb + (size_t)arow * DD + ks * 32 + kof);

    for (int cb = w; cb < 14; cb += 4) {
        f32x4 c = {0.f, 0.f, 0.f, 0.f};
        const int brow = cb * 16 + (lane & 15);
#pragma unroll
        for (int ks = 0; ks < 24; ks++) {
            short8 bf = *(const short8*)(vtb + (size_t)brow * DD + ks * 32 + kof);
            c = __builtin_amdgcn_mfma_f32_16x16x32_bf16(a[ks], bf, c, 0, 0, 0);
        }
        __hip_bfloat16* Gb = G + ((size_t)b * LP + rb * 16) * LP + cb * 16;
        const int col = lane & 15, rg = (lane >> 4) * 4;
#pragma unroll
        for (int r = 0; r < 4; r++) Gb[(size_t)(rg + r) * LP + col] = __float2bfloat16(c[r]);
    }
}

// Fused main: S = tf.vt^T (direct-from-L2, no LDS staging, no stage-1 barriers),
// softmax, num, T = P.G, den, logits.
// Grid (16, 64), 256 thr. Wave w owns l-blocks {w, w+4, w+8, w+12}.
// LDS: plds [64][PSTRIDE] bf16 + 3KB cross-wave exchange.
__global__ __launch_bounds__(256, 3) void main_kernel(
    const __hip_bfloat16* __restrict__ tf, const __hip_bfloat16* __restrict__ vt,
    const __hip_bfloat16* __restrict__ G, const float* __restrict__ qinv,
    float* __restrict__ logits) {
    const int b = blockIdx.y;
    const int n0 = blockIdx.x * 64;
    const int tid = threadIdx.x, w = tid >> 6, lane = tid & 63;
    const int g = lane >> 4, c = lane & 15;

    __shared__ __align__(16) unsigned char smem[29184 + 3072];
    unsigned short* plds = (unsigned short*)smem;            // [64][PSTRIDE]
    float* mx = (float*)(smem + 29184);                      // [64][4]
    float* sm = mx + 256;                                    // [64][4]
    float* nm = sm + 256;                                    // [64][4]

    const short* tfp = (const short*)tf;
    const short* vtb = (const short*)(vt + (size_t)b * LP * DD);

    // ---- Stage 1: S = tf . vt^T, K-sliced, operands straight from L2 ----
    f32x4 acc[4][4];  // [i = lb slot][nb]
#pragma unroll
    for (int i = 0; i < 4; i++)
#pragma unroll
        for (int nb = 0; nb < 4; nb++) acc[i][nb] = {0.f, 0.f, 0.f, 0.f};

    for (int ks = 0; ks < 24; ks++) {
        short8 a[4];
#pragma unroll
        for (int nb = 0; nb < 4; nb++)
            a[nb] = *(const short8*)(tfp + (size_t)(n0 + nb * 16 + c) * DD + ks * 32 + g * 8);
#pragma unroll
        for (int i = 0; i < 4; i++) {
            const int lb = w + 4 * i;
            if (lb < 14) {
                short8 bf = *(const short8*)(vtb + (size_t)(lb * 16 + c) * DD + ks * 32 + g * 8);
#pragma unroll
                for (int nb = 0; nb < 4; nb++)
                    acc[i][nb] = __builtin_amdgcn_mfma_f32_16x16x32_bf16(a[nb], bf, acc[i][nb], 0, 0, 0);
            }
        }
    }

    // ---- Stage 2: softmax over l (cross-wave: waves hold disjoint l-columns) ----
    const float inv_sqrtD = 0.0360843918f;
    float mp[4][4];
#pragma unroll
    for (int nb = 0; nb < 4; nb++)
#pragma unroll
        for (int r = 0; r < 4; r++) mp[nb][r] = -1e30f;
#pragma unroll
    for (int i = 0; i < 4; i++) {
        const int lb = w + 4 * i;
        if (lb < 14) {
            const int l = lb * 16 + c;
            if (l < LL) {
#pragma unroll
                for (int nb = 0; nb < 4; nb++)
#pragma unroll
                    for (int r = 0; r < 4; r++) mp[nb][r] = fmaxf(mp[nb][r], acc[i][nb][r]);
            }
        }
    }
#pragma unroll
    for (int nb = 0; nb < 4; nb++)
#pragma unroll
        for (int r = 0; r < 4; r++) mp[nb][r] = grpMax(mp[nb][r]);
    if (c == 0) {
#pragma unroll
        for (int nb = 0; nb < 4; nb++)
#pragma unroll
            for (int r = 0; r < 4; r++) mx[(nb * 16 + g * 4 + r) * 4 + w] = mp[nb][r];
    }
    __syncthreads();
    float mf[4][4];
#pragma unroll
    for (int nb = 0; nb < 4; nb++)
#pragma unroll
        for (int r = 0; r < 4; r++) {
            const int row = nb * 16 + g * 4 + r;
            mf[nb][r] = fmaxf(fmaxf(mx[row * 4 + 0], mx[row * 4 + 1]),
                              fmaxf(mx[row * 4 + 2], mx[row * 4 + 3]));
        }

    float sp[4][4], np[4][4];
#pragma unroll
    for (int nb = 0; nb < 4; nb++)
#pragma unroll
        for (int r = 0; r < 4; r++) { sp[nb][r] = 0.f; np[nb][r] = 0.f; }
#pragma unroll
    for (int i = 0; i < 4; i++) {
        const int lb = w + 4 * i;
        if (lb < 14) {
            const int l = lb * 16 + c;
#pragma unroll
            for (int nb = 0; nb < 4; nb++)
#pragma unroll
                for (int r = 0; r < 4; r++) {
                    const float raw = acc[i][nb][r];
                    const float p = (l < LL) ? __expf((raw - mf[nb][r]) * inv_sqrtD) : 0.f;
                    acc[i][nb][r] = p;
                    sp[nb][r] += p;
                    np[nb][r] += p * raw;
                }
        }
    }
#pragma unroll
    for (int nb = 0; nb < 4; nb++)
#pragma unroll
        for (int r = 0; r < 4; r++) { sp[nb][r] = grpSum(sp[nb][r]); np[nb][r] = grpSum(np[nb][r]); }
    if (c == 0) {
#pragma unroll
        for (int nb = 0; nb < 4; nb++)
#pragma unroll
            for (int r = 0; r < 4; r++) {
                const int row = nb * 16 + g * 4 + r;
                sm[row * 4 + w] = sp[nb][r];
                nm[row * 4 + w] = np[nb][r];
            }
    }
    __syncthreads();

    float invs[4][4];
#pragma unroll
    for (int nb = 0; nb < 4; nb++)
#pragma unroll
        for (int r = 0; r < 4; r++) {
            const int row = nb * 16 + g * 4 + r;
            const float ssum = sm[row * 4 + 0] + sm[row * 4 + 1] + sm[row * 4 + 2] + sm[row * 4 + 3];
            invs[nb][r] = 1.f / ssum;
        }

    // write normalized P (bf16) to plds [64][PSTRIDE]
#pragma unroll
    for (int i = 0; i < 4; i++) {
        const int lb = w + 4 * i;
        if (lb < 14) {
#pragma unroll
            for (int nb = 0; nb < 4; nb++)
#pragma unroll
                for (int r = 0; r < 4; r++)
                    plds[(size_t)(nb * 16 + g * 4 + r) * PSTRIDE + lb * 16 + c] =
                        f2bf(acc[i][nb][r] * invs[nb][r]);
        }
    }
    __syncthreads();

    // ---- Stage 3: T = P.G (lb-outer, G rows direct from L2), den = sum P*T ----
    // den reuses live acc (acc[i][nb][r] = unnormalized P at exactly (n,l) of t[r]).
    const short* Gb = (const short*)(G + (size_t)b * LP * LP);
    float den[4][4];
#pragma unroll
    for (int nb = 0; nb < 4; nb++)
#pragma unroll
        for (int r = 0; r < 4; r++) den[nb][r] = 0.f;

#pragma unroll
    for (int i = 0; i < 4; i++) {
        const int lb = w + 4 * i;
        if (lb < 14) {
            short8 gbv[7];
#pragma unroll
            for (int kb = 0; kb < 7; kb++)
                gbv[kb] = *(const short8*)(Gb + (size_t)(lb * 16 + c) * LP + kb * 32 + g * 8);
#pragma unroll
            for (int nb = 0; nb < 4; nb++) {
                f32x4 t = {0.f, 0.f, 0.f, 0.f};
#pragma unroll
                for (int kb = 0; kb < 7; kb++) {
                    short8 pa = *(const short8*)(plds + (size_t)(nb * 16 + c) * PSTRIDE + kb * 32 + g * 8);
                    t = __builtin_amdgcn_mfma_f32_16x16x32_bf16(pa, gbv[kb], t, 0, 0, 0);
                }
#pragma unroll
                for (int r = 0; r < 4; r++)
                    den[nb][r] += acc[i][nb][r] * invs[nb][r] * t[r];
            }
        }
    }

    // cross-wave den reduce + epilogue
#pragma unroll
    for (int nb = 0; nb < 4; nb++)
#pragma unroll
        for (int r = 0; r < 4; r++) den[nb][r] = grpSum(den[nb][r]);
    __syncthreads();
    if (c == 0) {
#pragma unroll
        for (int nb = 0; nb < 4; nb++)
#pragma unroll
            for (int r = 0; r < 4; r++) mx[(nb * 16 + g * 4 + r) * 4 + w] = den[nb][r];
    }
    __syncthreads();
    if (tid < 64) {
        const int row = tid;
        const int n = n0 + row;
        const float dsum = mx[row * 4 + 0] + mx[row * 4 + 1] + mx[row * 4 + 2] + mx[row * 4 + 3];
        const float ssum = sm[row * 4 + 0] + sm[row * 4 + 1] + sm[row * 4 + 2] + sm[row * 4 + 3];
        const float nsum = nm[row * 4 + 0] + nm[row * 4 + 1] + nm[row * 4 + 2] + nm[row * 4 + 3];
        const float num = nsum / ssum;
        const float dn = fmaxf(sqrtf(fmaxf(dsum, 0.f)), NORM_EPS);
        logits[(size_t)n * BB + b] = num * qinv[n] / dn;
    }
}

__global__ __launch_bounds__(64) void loss_row_kernel(
    const float* __restrict__ logits, const int* __restrict__ gm,
    const float* __restrict__ logtemp, float* __restrict__ scaled,
    float* __restrict__ posv, float* __restrict__ rowloss) {
    const int n = blockIdx.x;
    const int b = threadIdx.x;
    const float invtemp = 1.f / expf(logtemp[0]);
    const float e = expf(logits[(size_t)n * BB + b] * invtemp);
    scaled[(size_t)n * BB + b] = e;
    const float sum = waveSum(e);
    const int g = gm[n];
    const float pos = __shfl(e, g, 64);
    if (b == 0) {
        posv[n] = pos;
        rowloss[n] = -logf(pos / (sum + EPS) + EPS);
    }
}

__global__ __launch_bounds__(256) void colsum_kernel(
    const float* __restrict__ scaled, const int* __restrict__ gm,
    float* __restrict__ colsum, float* __restrict__ poscol) {
    const int b = blockIdx.x;
    const int tid = threadIdx.x;
    float s = 0.f, p = 0.f;
    for (int n = tid; n < NN; n += 256) {
        const float e = scaled[(size_t)n * BB + b];
        s += e;
        if (gm[n] == b) p += e;
    }
    s = waveSum(s); p = waveSum(p);
    __shared__ float red[8];
    const int w = tid >> 6;
    if ((tid & 63) == 0) { red[w] = s; red[4 + w] = p; }
    __syncthreads();
    if (tid == 0) {
        colsum[b] = red[0] + red[1] + red[2] + red[3];
        poscol[b] = red[4] + red[5] + red[6] + red[7];
    }
}

__global__ __launch_bounds__(1024) void final_kernel(
    const float* __restrict__ posv, const float* __restrict__ rowloss,
    const float* __restrict__ colsum, const float* __restrict__ poscol,
    const int* __restrict__ gm, float* __restrict__ out) {
    const int n = threadIdx.x;
    const int g = gm[n];
    const float pos = posv[n];
    const float sum_neg = colsum[g] - poscol[g];
    const float cl = -logf(pos / (pos + sum_neg + EPS) + EPS);
    float v = rowloss[n] + cl;
    v = waveSum(v);
    __shared__ float red[16];
    if ((n & 63) == 0) red[n >> 6] = v;
    __syncthreads();
    if (n == 0) {
        float s = 0.f;
#pragma unroll
        for (int i = 0; i < 16; i++) s += red[i];
        out[0] = s / (2.f * NN);
    }
}

extern "C" void kernel_launch(void* const* d_in, const int* in_sizes, int n_in,
                              void* d_out, int out_size, void* d_ws, size_t ws_size,
                              hipStream_t stream) {
    const float* text = (const float*)d_in[0];
    const float* vis = (const float*)d_in[1];
    const int* gm = (const int*)d_in[2];
    const float* gamma = (const float*)d_in[3];
    const float* beta = (const float*)d_in[4];
    const float* logtemp = (const float*)d_in[5];
    float* out = (float*)d_out;

    char* w = (char*)d_ws;
    __hip_bfloat16* tf = (__hip_bfloat16*)w;             w += (size_t)NN * DD * 2;
    __hip_bfloat16* vt = (__hip_bfloat16*)w;             w += (size_t)BB * LP * DD * 2;
    __hip_bfloat16* G  = (__hip_bfloat16*)w;             w += (size_t)BB * LP * LP * 2;
    float* qinv    = (float*)w;  w += (size_t)NN * 4;
    float* logits  = (float*)w;  w += (size_t)NN * BB * 4;
    float* scaled  = (float*)w;  w += (size_t)NN * BB * 4;
    float* posv    = (float*)w;  w += (size_t)NN * 4;
    float* rowloss = (float*)w;  w += (size_t)NN * 4;
    float* colsum  = (float*)w;  w += (size_t)BB * 4;
    float* poscol  = (float*)w;  w += (size_t)BB * 4;

    ln_kernel<<<NN, 256, 0, stream>>>(text, tf, gamma, beta, qinv);
    ln_vis_kernel<<<BB * LP, 256, 0, stream>>>(vis, vt, gamma, beta);

    gram_kernel<<<dim3(14, BB), 256, 0, stream>>>(vt, G);
    main_kernel<<<dim3(NN / 64, BB), 256, 0, stream>>>(tf, vt, G, qinv, logits);

    loss_row_kernel<<<NN, 64, 0, stream>>>(logits, gm, logtemp, scaled, posv, rowloss);
    colsum_kernel<<<BB, 256, 0, stream>>>(scaled, gm, colsum, poscol);
    final_kernel<<<1, 1024, 0, stream>>>(posv, rowloss, colsum, poscol, gm, out);
}